// Round 13
// baseline (403.906 us; speedup 1.0000x reference)
//
#include <hip/hip_runtime.h>
#include <hip/hip_bf16.h>
#include <math.h>

#define BB 4
#define LL 2048
#define DM 512
#define NH 8
#define DK 64
#define RANK 20

typedef __attribute__((ext_vector_type(8))) short short8;
typedef __attribute__((ext_vector_type(4))) short short4b;
typedef __attribute__((ext_vector_type(4))) float f32x4;
typedef __hip_bfloat16 bf16;

__device__ inline short to_bf(float x) {
    bf16 h = __float2bfloat16(x);
    return *reinterpret_cast<short*>(&h);
}
__device__ inline unsigned pk2(float lo, float hi) {
    return ((unsigned)(unsigned short)to_bf(hi) << 16) |
           (unsigned)(unsigned short)to_bf(lo);
}

// ---------------- build W^T (bf16) from TT cores, all 4 sets ----------------
struct BwArgs {
    const float* g1[4]; const float* g2[4]; const float* g3[4]; const float* g4[4];
    bf16* wt[4];
};
__global__ __launch_bounds__(256) void build_w_kernel(BwArgs args)
{
    int s4 = blockIdx.y;
    const float* __restrict__ g1 = args.g1[s4];
    const float* __restrict__ g2 = args.g2[s4];
    const float* __restrict__ g3 = args.g3[s4];
    const float* __restrict__ g4 = args.g4[s4];
    bf16* __restrict__ Wt = args.wt[s4];

    int idx = blockIdx.x * 256 + threadIdx.x;
    if (idx >= 4*4*8*4*4*8) return;
    int q = idx & 7; int t = idx >> 3;
    int p = t & 3;  t >>= 2;
    int o = t & 3;  t >>= 2;
    int y = t & 7;  t >>= 3;
    int x = t & 3;  t >>= 2;
    int w = t & 3;

    float c[RANK];
    for (int v = 0; v < RANK; ++v) c[v] = 0.f;
    for (int u = 0; u < RANK; ++u) {
        float a = g1[(w*4 + o)*RANK + u];
        const float* g2p = g2 + ((u*4 + x)*4 + p)*RANK;
        for (int v = 0; v < RANK; ++v) c[v] += a * g2p[v];
    }
    float d[RANK];
    for (int r = 0; r < RANK; ++r) d[r] = 0.f;
    for (int v = 0; v < RANK; ++v) {
        float cv = c[v];
        const float* g3p = g3 + ((v*8 + y)*8 + q)*RANK;
        for (int r = 0; r < RANK; ++r) d[r] += cv * g3p[r];
    }
    for (int z = 0; z < 4; ++z) {
        for (int s = 0; s < 4; ++s) {
            float acc = 0.f;
            for (int r = 0; r < RANK; ++r) acc += d[r] * g4[(r*4 + z)*4 + s];
            int i = ((w*4 + x)*8 + y)*4 + z;
            int j = ((o*4 + p)*8 + q)*4 + s;
            Wt[(size_t)j*DM + i] = __float2bfloat16(acc);
        }
    }
}

// ---------------- qkv projections, fused fp32->bf16 A conversion ----------------
// z=0 q (scaled by log2e/8, head layout), z=1 k (head layout),
// z=2 v (transposed [bh][d][l]).  A read as fp32, packed with to_bf (bit-identical
// to the old standalone cvt kernel).
struct QkvArgs {
    const float* A[3]; const bf16* W[3]; const float* bias[3];
    bf16* outQ; bf16* outK; bf16* outV;
};
__global__ __launch_bounds__(256) void gemm_qkv_kernel(QkvArgs args)
{
    int z = blockIdx.z;
    const float* __restrict__ A  = args.A[z];
    const bf16* __restrict__ Wt = args.W[z];
    const float* __restrict__ bias = args.bias[z];

    int m0 = blockIdx.x * 64, n0 = blockIdx.y * 64;
    int t = threadIdx.x, lane = t & 63, wave = t >> 6;
    int l15 = lane & 15, l4 = lane >> 4;
    int wm = wave >> 1, wn = wave & 1;
    const float* Ap = A  + (size_t)(m0 + wm*32)*DM;
    const bf16*  Bp = Wt + (size_t)(n0 + wn*32)*DM;

    f32x4 acc[2][2] = {};
    for (int k0 = 0; k0 < DM; k0 += 32) {
        short8 a[2], b[2];
        #pragma unroll
        for (int mt = 0; mt < 2; ++mt) {
            const float* ap = &Ap[(size_t)(mt*16 + l15)*DM + k0 + l4*8];
            float4 x0 = *(const float4*)ap;
            float4 x1 = *(const float4*)(ap + 4);
            short8 af;
            af[0]=to_bf(x0.x); af[1]=to_bf(x0.y); af[2]=to_bf(x0.z); af[3]=to_bf(x0.w);
            af[4]=to_bf(x1.x); af[5]=to_bf(x1.y); af[6]=to_bf(x1.z); af[7]=to_bf(x1.w);
            a[mt] = af;
        }
        #pragma unroll
        for (int nt = 0; nt < 2; ++nt)
            b[nt] = *(const short8*)&Bp[(size_t)(nt*16 + l15)*DM + k0 + l4*8];
        #pragma unroll
        for (int mt = 0; mt < 2; ++mt)
            #pragma unroll
            for (int nt = 0; nt < 2; ++nt)
                acc[mt][nt] = __builtin_amdgcn_mfma_f32_16x16x32_bf16(
                    a[mt], b[nt], acc[mt][nt], 0, 0, 0);
    }

    if (z < 2) {
        bf16* __restrict__ out = (z == 0) ? args.outQ : args.outK;
        // 0.125 * log2(e): fold softmax scale + exp2 conversion into Q
        float oscale = (z == 0) ? 0.18033688f : 1.0f;
        #pragma unroll
        for (int mt = 0; mt < 2; ++mt) {
            #pragma unroll
            for (int r = 0; r < 4; ++r) {
                int m = m0 + wm*32 + mt*16 + l4*4 + r;
                int l = m & (LL-1), bb = m >> 11;
                #pragma unroll
                for (int nt = 0; nt < 2; ++nt) {
                    int n = n0 + wn*32 + nt*16 + l15;
                    int h = n >> 6, d = n & 63;
                    float val = (acc[mt][nt][r] + bias[n]) * oscale;
                    out[(((size_t)(bb*NH + h))*LL + l)*DK + d] = __float2bfloat16(val);
                }
            }
        }
    } else {
        // transposed store: vt[(bh*DK + d)*LL + l]
        #pragma unroll
        for (int mt = 0; mt < 2; ++mt) {
            int mbase = m0 + wm*32 + mt*16 + l4*4;
            int l = mbase & (LL-1), bb = mbase >> 11;
            #pragma unroll
            for (int nt = 0; nt < 2; ++nt) {
                int n = n0 + wn*32 + nt*16 + l15;
                int h = n >> 6, d = n & 63;
                float bv = bias[n];
                short4b h4;
                #pragma unroll
                for (int r = 0; r < 4; ++r) h4[r] = to_bf(acc[mt][nt][r] + bv);
                *(short4b*)&args.outV[((size_t)(bb*NH + h)*DK + d)*LL + l] = h4;
            }
        }
    }
}

// fc GEMM: A = o (bf16 row-major), out fp32 row-major + bias
__global__ __launch_bounds__(256) void gemm_fc_kernel(
    const bf16* __restrict__ A, const bf16* __restrict__ Wt,
    const float* __restrict__ bias, float* __restrict__ out)
{
    int m0 = blockIdx.x * 64, n0 = blockIdx.y * 64;
    int t = threadIdx.x, lane = t & 63, wave = t >> 6;
    int l15 = lane & 15, l4 = lane >> 4;
    int wm = wave >> 1, wn = wave & 1;
    const bf16* Ap = A  + (size_t)(m0 + wm*32)*DM;
    const bf16* Bp = Wt + (size_t)(n0 + wn*32)*DM;

    f32x4 acc[2][2] = {};
    for (int k0 = 0; k0 < DM; k0 += 32) {
        short8 a[2], b[2];
        #pragma unroll
        for (int mt = 0; mt < 2; ++mt)
            a[mt] = *(const short8*)&Ap[(size_t)(mt*16 + l15)*DM + k0 + l4*8];
        #pragma unroll
        for (int nt = 0; nt < 2; ++nt)
            b[nt] = *(const short8*)&Bp[(size_t)(nt*16 + l15)*DM + k0 + l4*8];
        #pragma unroll
        for (int mt = 0; mt < 2; ++mt)
            #pragma unroll
            for (int nt = 0; nt < 2; ++nt)
                acc[mt][nt] = __builtin_amdgcn_mfma_f32_16x16x32_bf16(
                    a[mt], b[nt], acc[mt][nt], 0, 0, 0);
    }

    #pragma unroll
    for (int mt = 0; mt < 2; ++mt) {
        #pragma unroll
        for (int r = 0; r < 4; ++r) {
            int m = m0 + wm*32 + mt*16 + l4*4 + r;
            #pragma unroll
            for (int nt = 0; nt < 2; ++nt) {
                int n = n0 + wn*32 + nt*16 + l15;
                out[(size_t)m*DM + n] = acc[mt][nt][r] + bias[n];
            }
        }
    }
}

// ---------------- attention pass A: 32 q-rows/wave, K dbuf, 1 barrier/chunk ----
// SWAPPED QK: S^T = mfma(K, Q). K chunk i+1 global-loaded to regs at top of
// chunk i (latency hidden), ds-written to alternate buffer after PV, single
// barrier per chunk.
__global__ __launch_bounds__(256, 2) void attn_a_kernel(
    const bf16* __restrict__ Qh, const bf16* __restrict__ Kh,
    const bf16* __restrict__ Vt, float* __restrict__ invl_g,
    bf16* __restrict__ O)
{
    __shared__ __align__(16) bf16 Ks[2][128*64];    // 32 KB double-buffered
    __shared__ __align__(16) bf16 Ps[4][32*128];    // 32 KB  (row q: 256B)
    __shared__ float invlS[4][32];

    int qt = blockIdx.x, bh = blockIdx.y;
    int q0 = qt * 128;
    int t = threadIdx.x, lane = t & 63, wave = t >> 6;
    int l15 = lane & 15, l4 = lane >> 4;
    int qr0 = wave * 32;

    const bf16* Qp = Qh + ((size_t)bh * LL + q0 + qr0) * DK;
    const bf16* Kp = Kh + (size_t)bh * LL * DK;
    const bf16* Vp = Vt + (size_t)bh * DK * LL;

    short8 aq0[2], aq1[2];
    #pragma unroll
    for (int f = 0; f < 2; ++f) {
        aq0[f] = *(const short8*)&Qp[(size_t)(f*16 + l15)*DK + l4*8];
        aq1[f] = *(const short8*)&Qp[(size_t)(f*16 + l15)*DK + 32 + l4*8];
    }

    int srow = t >> 3, sseg = t & 7;       // staging: 32 rows x 8 16B-segs x4
    int swr = (l15 & 7) << 4;
    int soff = (sseg*16) ^ ((srow & 7) << 4);   // (srow+i*32)&7 == srow&7

    float lsum[2] = {0.f, 0.f};
    f32x4 o_acc[2][4] = {};

    // prologue: chunk 0 -> regs -> buf0
    short8 kreg[4];
    #pragma unroll
    for (int i = 0; i < 4; ++i)
        kreg[i] = *(const short8*)&Kp[(size_t)(srow + i*32)*DK + sseg*8];
    #pragma unroll
    for (int i = 0; i < 4; ++i)
        *(short8*)&Ks[0][(srow + i*32)*64 + (soff >> 1)] = kreg[i];
    __syncthreads();

    for (int kc = 0; kc < LL; kc += 128) {
        int cur = (kc >> 7) & 1;
        bool more = (kc + 128) < LL;

        // issue next-chunk K loads early (hidden under this chunk's compute)
        if (more) {
            #pragma unroll
            for (int i = 0; i < 4; ++i)
                kreg[i] = *(const short8*)&Kp[(size_t)(kc + 128 + srow + i*32)*DK + sseg*8];
        }
        // prefetch V fragments for this chunk (consumed after QK)
        short8 vf[16];
        #pragma unroll
        for (int kt = 0; kt < 4; ++kt)
            #pragma unroll
            for (int dt = 0; dt < 4; ++dt)
                vf[kt*4 + dt] =
                    *(const short8*)&Vp[(size_t)(dt*16 + l15)*LL + kc + kt*32 + l4*8];

        const bf16* Kb = &Ks[cur][0];
        #pragma unroll
        for (int ct = 0; ct < 8; ++ct) {
            int rb = (ct*16 + l15) * 64;
            short8 k0f = *(const short8*)&Kb[rb + (((l4*16) ^ swr) >> 1)];
            short8 k1f = *(const short8*)&Kb[rb + (((64 + l4*16) ^ swr) >> 1)];
            #pragma unroll
            for (int f = 0; f < 2; ++f) {
                f32x4 s = {0.f, 0.f, 0.f, 0.f};
                s = __builtin_amdgcn_mfma_f32_16x16x32_bf16(k0f, aq0[f], s, 0, 0, 0);
                s = __builtin_amdgcn_mfma_f32_16x16x32_bf16(k1f, aq1[f], s, 0, 0, 0);
                float p0 = exp2f(s[0]), p1 = exp2f(s[1]);
                float p2 = exp2f(s[2]), p3 = exp2f(s[3]);
                lsum[f] += (p0 + p1) + (p2 + p3);
                uint2 w2;
                w2.x = pk2(p0, p1);
                w2.y = pk2(p2, p3);
                int kb = (ct*32 + l4*8) ^ swr;
                *(uint2*)((char*)&Ps[wave][(f*16 + l15)*128] + kb) = w2;
            }
        }

        #pragma unroll
        for (int f = 0; f < 2; ++f)
            #pragma unroll
            for (int kt = 0; kt < 4; ++kt) {
                short8 a = *(const short8*)
                    &Ps[wave][(f*16 + l15)*128 + (((kt*64 + l4*16) ^ swr) >> 1)];
                #pragma unroll
                for (int dt = 0; dt < 4; ++dt)
                    o_acc[f][dt] = __builtin_amdgcn_mfma_f32_16x16x32_bf16(
                        a, vf[kt*4 + dt], o_acc[f][dt], 0, 0, 0);
            }

        // write next chunk into the other buffer (no readers there this iter)
        if (more) {
            #pragma unroll
            for (int i = 0; i < 4; ++i)
                *(short8*)&Ks[cur ^ 1][(srow + i*32)*64 + (soff >> 1)] = kreg[i];
        }
        __syncthreads();
    }

    // reduce lsum across the 4 l4-groups (lanes sharing q = l15 within a frag)
    #pragma unroll
    for (int f = 0; f < 2; ++f) {
        float ss = lsum[f];
        ss += __shfl_xor(ss, 16);
        ss += __shfl_xor(ss, 32);
        float inv = 1.0f / ss;
        if (l4 == 0) {
            invl_g[(size_t)bh * LL + q0 + qr0 + f*16 + l15] = inv;
            invlS[wave][f*16 + l15] = inv;
        }
    }

    // write O = o_acc * invl (bf16)
    int bb = bh >> 3, h = bh & 7;
    #pragma unroll
    for (int f = 0; f < 2; ++f) {
        f32x4 iv = *(f32x4*)&invlS[wave][f*16 + l4*4];
        #pragma unroll
        for (int dt = 0; dt < 4; ++dt)
            #pragma unroll
            for (int r = 0; r < 4; ++r) {
                int row = q0 + qr0 + f*16 + l4*4 + r;
                O[((size_t)bb * LL + row) * DM + h*DK + dt*16 + l15] =
                    __float2bfloat16(o_acc[f][dt][r] * iv[r]);
            }
    }
}

// ---------------- attention pass B: normalized-P streamer ----------------
__global__ __launch_bounds__(256, 4) void attn_p_kernel(
    const bf16* __restrict__ Qh, const bf16* __restrict__ Kh,
    const float* __restrict__ invl_g, float* __restrict__ attn)
{
    __shared__ __align__(16) bf16 Ks[256*64];       // 32 KB, swizzled rows

    int ko = blockIdx.x, qt = blockIdx.y, bh = blockIdx.z;
    int kc0 = ko * 256, q0 = qt * 64;
    int t = threadIdx.x, lane = t & 63, wave = t >> 6;
    int l15 = lane & 15, l4 = lane >> 4;
    int qr0 = wave * 16;

    const bf16* Qp = Qh + ((size_t)bh * LL + q0 + qr0) * DK;
    const bf16* Kp = Kh + ((size_t)bh * LL + kc0) * DK;

    short8 bq0 = *(const short8*)&Qp[(size_t)l15*DK + l4*8];
    short8 bq1 = *(const short8*)&Qp[(size_t)l15*DK + 32 + l4*8];
    float inv = invl_g[(size_t)bh * LL + q0 + qr0 + l15];

    #pragma unroll
    for (int g = 0; g < 8; ++g) {
        int off = (g*16) ^ ((t & 7) << 4);
        *(short8*)&Ks[t*64 + (off >> 1)] =
            *(const short8*)&Kp[(size_t)t*DK + g*8];
    }
    __syncthreads();

    int swr = (l15 & 7) << 4;
    float* ap = attn + ((size_t)bh * LL + q0 + qr0 + l15) * LL + kc0;

    #pragma unroll 4
    for (int ct = 0; ct < 16; ++ct) {
        int rb = (ct*16 + l15) * 64;
        short8 a0 = *(const short8*)&Ks[rb + (((l4*16) ^ swr) >> 1)];
        short8 a1 = *(const short8*)&Ks[rb + (((64 + l4*16) ^ swr) >> 1)];
        f32x4 s = {0.f, 0.f, 0.f, 0.f};
        s = __builtin_amdgcn_mfma_f32_16x16x32_bf16(a0, bq0, s, 0, 0, 0);
        s = __builtin_amdgcn_mfma_f32_16x16x32_bf16(a1, bq1, s, 0, 0, 0);
        float4 o;
        o.x = exp2f(s[0]) * inv;
        o.y = exp2f(s[1]) * inv;
        o.z = exp2f(s[2]) * inv;
        o.w = exp2f(s[3]) * inv;
        *(float4*)&ap[ct*16 + l4*4] = o;
    }
}

// ---------------- residual + LayerNorm ----------------
__global__ __launch_bounds__(256) void ln_kernel(
    const float* __restrict__ Y, const float* __restrict__ Res,
    const float* __restrict__ g, const float* __restrict__ bta,
    float* __restrict__ out)
{
    int row = blockIdx.x;
    int t = threadIdx.x;
    const float* yp = Y  + (size_t)row*DM;
    const float* rp = Res + (size_t)row*DM;
    float v0 = yp[t]       + rp[t];
    float v1 = yp[t + 256] + rp[t + 256];
    float s1 = v0 + v1;
    float s2 = v0*v0 + v1*v1;
    __shared__ float red1[4], red2[4];
    #pragma unroll
    for (int off = 32; off >= 1; off >>= 1) {
        s1 += __shfl_xor(s1, off);
        s2 += __shfl_xor(s2, off);
    }
    int w = t >> 6;
    if ((t & 63) == 0) { red1[w] = s1; red2[w] = s2; }
    __syncthreads();
    float mu = (red1[0]+red1[1]+red1[2]+red1[3]) * (1.0f/DM);
    float ms = (red2[0]+red2[1]+red2[2]+red2[3]) * (1.0f/DM);
    float inv = rsqrtf(ms - mu*mu + 1e-12f);
    out[(size_t)row*DM + t]       = (v0 - mu)*inv*g[t]       + bta[t];
    out[(size_t)row*DM + t + 256] = (v1 - mu)*inv*g[t + 256] + bta[t + 256];
}

extern "C" void kernel_launch(void* const* d_in, const int* in_sizes, int n_in,
                              void* d_out, int out_size, void* d_ws, size_t ws_size,
                              hipStream_t stream)
{
    const float* G[4][5];
    for (int s = 0; s < 4; ++s)
        for (int i = 0; i < 5; ++i)
            G[s][i] = (const float*)d_in[s*5 + i];
    const float* q   = (const float*)d_in[20];
    const float* k   = (const float*)d_in[21];
    const float* v   = (const float*)d_in[22];
    const float* lng = (const float*)d_in[23];
    const float* lnb = (const float*)d_in[24];

    float* out  = (float*)d_out;                         // [B,L,DM]
    float* attn = out + (size_t)BB*LL*DM;                // [B,NH,L,L]

    const size_t NTOK = (size_t)BB*LL*DM;                // 4.19M elems
    bf16* wt  = (bf16*)d_ws;                             // 4*512*512 bf16
    bf16* qh  = wt + 4*(size_t)DM*DM;                    // [bh][l][dk]
    bf16* kh  = qh + NTOK;
    bf16* vt  = kh + NTOK;                               // [bh][dk][l]
    bf16* o   = vt + NTOK;                               // [b][l][dm]
    float* y  = (float*)(o + NTOK);                      // [b][l][dm] f32
    float* invl = y + NTOK;                              // [bh][l] f32 row inv-sums

    // build all 4 W^T
    BwArgs bw;
    for (int s = 0; s < 4; ++s) {
        bw.g1[s] = G[s][0]; bw.g2[s] = G[s][1];
        bw.g3[s] = G[s][2]; bw.g4[s] = G[s][3];
        bw.wt[s] = wt + (size_t)s*DM*DM;
    }
    build_w_kernel<<<dim3(64, 4), 256, 0, stream>>>(bw);

    // projections (64x64 tiles, fused fp32->bf16 A conversion)
    QkvArgs qa;
    qa.A[0] = q; qa.A[1] = k; qa.A[2] = v;
    qa.W[0] = wt; qa.W[1] = wt + (size_t)DM*DM; qa.W[2] = wt + 2*(size_t)DM*DM;
    qa.bias[0] = G[0][4]; qa.bias[1] = G[1][4]; qa.bias[2] = G[2][4];
    qa.outQ = qh; qa.outK = kh; qa.outV = vt;
    gemm_qkv_kernel<<<dim3(BB*LL/64, DM/64, 3), 256, 0, stream>>>(qa);

    // attention pass A: 128 q-rows/block, 32 q-rows/wave, K dbuf
    attn_a_kernel<<<dim3(LL/128, BB*NH), 256, 0, stream>>>(qh, kh, vt, invl, o);

    // attention pass B: normalized-P streamer (no barriers in store loop)
    attn_p_kernel<<<dim3(LL/256, LL/64, BB*NH), 256, 0, stream>>>(qh, kh, invl, attn);

    // fc + LN
    gemm_fc_kernel<<<dim3(BB*LL/64, DM/64), 256, 0, stream>>>(
        o, wt + 3*(size_t)DM*DM, G[3][4], y);
    ln_kernel<<<BB*LL, 256, 0, stream>>>(y, q, lng, lnb, out);
}